// Round 9
// baseline (219.151 us; speedup 1.0000x reference)
//
#include <hip/hip_runtime.h>
#include <math.h>

// SampleScoreModel fused flash kernel — fp32 in/out.
// R18 (resubmit; previous round was an infra failure, bench never ran).
// One-barrier pipeline. R17 (127.5us flash) had 2 full-drain barriers
// per tile and 49 ds_read_b128/wave-tile with nothing saturated ->
// latency/serialization-bound. Changes:
//  - V is NOT staged in LDS: each split's V slice (512KB) is L2-resident and
//    PV's reads coalesce perfectly (1KB/b128) -> read gvt directly from
//    global. Kills 16/49 LDS reads + 4 GL16s/wave-tile + the vt swizzle.
//  - Freed 32KB -> K double-buffer (khi/klo x2 = 64KB + p 5KB = 70656B,
//    same 2 blocks/CU). B2 eliminated: K(t+1) GL16s go into buf^1 right
//    after B1 (all waves provably past their buf^1 reads at the previous
//    barrier). ONE __syncthreads per tile (its implicit vmcnt(0) drain is
//    the staging fence -> same m97-safe discipline as R17).
//  - prep_rows + prep_t merged into one kernel (prep_t reads smp directly;
//    gvt stored PLAIN transposed, no swizzle). 4 launches -> 3.
// Kept: (256,2), ns=8 (512 blocks = exact 2/CU), pre-swizzled K planes +
// read-side XOR (R15-R17 verified), GL16 offset=0 rule, defer-max, setprio,
// tflag hoist.

typedef float  f32x4 __attribute__((ext_vector_type(4)));
typedef short  s16x8 __attribute__((ext_vector_type(8)));
typedef unsigned short u16;

#define LOG2E   1.44269504088896f
#define L2_10K  13.2877123795494f   /* log2(10000) */
#define L2_001 -6.64385618977472f   /* log2(0.01)  */
#define SMIN2   1e-8f               /* SIGMA_MIN^2 */
#define DDIM    256
#define DEFER_THR 12.0f             /* log2-domain defer-max threshold */

#if defined(__has_builtin)
#if __has_builtin(__builtin_amdgcn_exp2f)
#define EXP2(x) __builtin_amdgcn_exp2f(x)
#endif
#endif
#ifndef EXP2
#define EXP2(x) exp2f(x)
#endif

// global -> LDS direct copy, 16B/lane. offset=0 ALWAYS (R15 lesson: the imm
// offset applies to the LDS side; baking offsets into both pointers is safe
// under either semantics). LDS dest = uniform base + lane*16.
#define GL16(gp, lp) \
  __builtin_amdgcn_global_load_lds( \
      (const __attribute__((address_space(1))) unsigned int*)(gp), \
      (__attribute__((address_space(3))) unsigned int*)(lp), 16, 0, 0)

__device__ __forceinline__ u16 bf16_rne(float f) {
  unsigned int u = __builtin_bit_cast(unsigned int, f);
  u = (u + 0x7FFFu + ((u >> 16) & 1u)) >> 16;
  return (u16)u;
}
__device__ __forceinline__ float bf16_to_f(u16 h) {
  unsigned int u = ((unsigned int)h) << 16;
  return __builtin_bit_cast(float, u);
}
__device__ __forceinline__ float f16_to_f(u16 h) {
  int s = (h >> 15) & 1, e = (h >> 10) & 31, m = h & 1023;
  float v;
  if (e == 0)       v = ldexpf((float)m, -24);
  else if (e == 31) v = 3.0e38f;
  else              v = ldexpf((float)(1024 + m), e - 25);
  return s ? -v : v;
}

// t-dtype insurance (returns fp32-mode on genuine fp32 t~U[0,1)).
__device__ __forceinline__ int classify_t_dtype(const void* tp) {
  const u16*          u16p = (const u16*)tp;
  const unsigned int* u32p = (const unsigned int*)tp;
  int c16 = 0, c32 = 0;
  for (int i = 0; i < 128; ++i) {
    u16 u = u16p[i];
    int e = (u >> 7) & 0xFF;
    if (!(u & 0x8000) && e >= 113 && e <= 126) c16++;
  }
  for (int i = 0; i < 64; ++i) {
    unsigned int w = u32p[i];
    int e = (int)((w >> 23) & 0xFF);
    if (!(w & 0x80000000u) && e >= 113 && e <= 126) c32++;
  }
  if (c32 >= 51) return (c16 >= 102) ? 0 : 1;   // 0=bf16, 1=fp32
  return 2;                                      // 2=fp16
}
__device__ __forceinline__ float load_t(const void* tp, int i, int mode) {
  float v;
  if (mode == 0)      v = bf16_to_f(((const u16*)tp)[i]);
  else if (mode == 1) v = ((const float*)tp)[i];
  else                v = f16_to_f(((const u16*)tp)[i]);
  return fminf(fmaxf(v, 0.f), 1.f);
}

// ---------------- merged precompute kernel ----------------
// Blocks [0, N/4):      bf16 hi/lo K planes, PRE-SWIZZLED (chunk ci at slot
//                       ci^(row&7)), + 0.5*||s||^2, + t-dtype flag.
// Blocks [N/4, N/4+N/32): plain tile-blocked transposed V (bf16 hi):
//                       gvt[(n0/32)*256 + d][n] = bf16(V[n0+n][d]).
__global__ __launch_bounds__(256)
void prep_all(const float* __restrict__ smp, const void* __restrict__ t,
              u16* __restrict__ gkhi, u16* __restrict__ gklo,
              float* __restrict__ gs2, u16* __restrict__ gvt,
              int* __restrict__ tflag, int N)
{
  int nb_rows = N >> 2;
  if ((int)blockIdx.x < nb_rows) {
    if (blockIdx.x == 0 && threadIdx.x == 0) *tflag = classify_t_dtype(t);
    int row  = blockIdx.x * 4 + (threadIdx.x >> 6);
    int lane = threadIdx.x & 63;
    float4 v4 = *(const float4*)(smp + (size_t)row * DDIM + lane * 4);
    float v[4] = {v4.x, v4.y, v4.z, v4.w};
    ushort4 h, l;
    u16 hh[4], ll[4];
    float s2 = 0.f;
#pragma unroll
    for (int e = 0; e < 4; ++e) {
      hh[e] = bf16_rne(v[e]);
      ll[e] = bf16_rne(v[e] - bf16_to_f(hh[e]));
      s2 = fmaf(v[e], v[e], s2);
    }
    h.x = hh[0]; h.y = hh[1]; h.z = hh[2]; h.w = hh[3];
    l.x = ll[0]; l.y = ll[1]; l.z = ll[2]; l.w = ll[3];
    int ci  = lane >> 1;                                  // chunk 0..31
    int col = (((ci ^ (row & 7)) << 3) | ((lane & 1) << 2));
    *(ushort4*)(gkhi + (size_t)row * DDIM + col) = h;
    *(ushort4*)(gklo + (size_t)row * DDIM + col) = l;
#pragma unroll
    for (int msk = 1; msk <= 32; msk <<= 1) s2 += __shfl_xor(s2, msk);
    if (lane == 0) gs2[row] = 0.5f * s2;
  } else {
    int bt = blockIdx.x - nb_rows;
    int d  = threadIdx.x;
    int n0 = bt * 32;
    u16 buf[32];
#pragma unroll
    for (int i = 0; i < 32; ++i)
      buf[i] = bf16_rne(smp[(size_t)(n0 + i) * DDIM + d]);  // coalesced
    u16* dst = gvt + ((size_t)bt * 256 + d) * 32;
#pragma unroll
    for (int c = 0; c < 4; ++c)
      *(s16x8*)(dst + c * 8) = *(s16x8*)&buf[c * 8];
  }
}

// ---------------- flash kernel ----------------

#define PSTR 40

struct __align__(16) Smem {
  u16 khi[2][32 * 256];  // 32768 B  dbuf; slot s of row r = chunk s^(r&7)
  u16 klo[2][32 * 256];  // 32768 B
  u16 p  [4][16 * PSTR]; //  5120 B  per-wave P round-trip
};  // 70656 B -> 2 blocks/CU (<= 81920)

__global__ __launch_bounds__(256, 2)
void flash_kernel(const void* __restrict__ t, const float* __restrict__ x,
                  const u16* __restrict__ gkhi, const u16* __restrict__ gklo,
                  const u16* __restrict__ gvt, const float* __restrict__ gs2,
                  const int* __restrict__ tflag, float* __restrict__ out,
                  float* __restrict__ pO, float* __restrict__ pm,
                  float* __restrict__ pl, int B, int N)
{
  __shared__ Smem sm;
  const int tid  = threadIdx.x;
  const int wave = tid >> 6, lane = tid & 63;
  const int lq = lane >> 4, lr = lane & 15;      // quad, lane-in-quad
  const int m0 = blockIdx.x * 64 + wave * 16;    // wave owns 16 m-rows
  const int nsplit = gridDim.y, split = blockIdx.y;
  const int tiles_total = N >> 5;
  const int tq = tiles_total / nsplit, tr = tiles_total % nsplit;
  const int tile0 = split * tq + (split < tr ? split : tr);
  const int iters = tq + (split < tr ? 1 : 0);
  const int n0b = tile0 << 5;
  const int tmode = *tflag;

  float invd[4];
#pragma unroll
  for (int r = 0; r < 4; ++r) {
    int gm = m0 + lq * 4 + r;
    float tv = load_t(t, gm, tmode);
    float ts = EXP2(fmaf(tv, L2_10K, L2_001));
    invd[r] = LOG2E / (ts * ts + SMIN2);
  }

  // Q fragments (block-invariant): A-layout row = m0 + lr, k = ks*32 + lq*8 + j.
  s16x8 qhi[8], qlo[8];
  {
    const float* xr = x + (size_t)(m0 + lr) * DDIM;
#pragma unroll
    for (int ks = 0; ks < 8; ++ks) {
      const float4* p4 = (const float4*)(xr + ks * 32 + lq * 8);
      float4 a = p4[0], b = p4[1];
      float v[8] = {a.x, a.y, a.z, a.w, b.x, b.y, b.z, b.w};
#pragma unroll
      for (int j = 0; j < 8; ++j) {
        u16 h = bf16_rne(v[j]);
        u16 l = bf16_rne(v[j] - bf16_to_f(h));
        qhi[ks][j] = (short)h;
        qlo[ks][j] = (short)l;
      }
    }
  }

  f32x4 O[16];
#pragma unroll
  for (int dt = 0; dt < 16; ++dt) O[dt] = (f32x4){0.f, 0.f, 0.f, 0.f};
  float mrun[4], lrun[4];
#pragma unroll
  for (int r = 0; r < 4; ++r) { mrun[r] = -1e30f; lrun[r] = 0.f; }

  const int krsw = lr & 7;                       // K read swizzle key (row&7)
  const int wo = (wave << 12) + lane * 16;       // GL16 wave slice + lane off

  {  // prologue: stage K(t0) into buf 0
    size_t tb = (size_t)n0b << 9;
    const char* gk = (const char*)gkhi + tb + wo;
    const char* gl = (const char*)gklo + tb + wo;
    char* lk = (char*)sm.khi[0] + (wave << 12);
    char* ll = (char*)sm.klo[0] + (wave << 12);
    GL16(gk,        lk);        GL16(gk + 1024, lk + 1024);
    GL16(gk + 2048, lk + 2048); GL16(gk + 3072, lk + 3072);
    GL16(gl,        ll);        GL16(gl + 1024, ll + 1024);
    GL16(gl + 2048, ll + 2048); GL16(gl + 3072, ll + 3072);
  }

  int n0 = n0b, cur = 0;
  for (int it = 0; it < iters; ++it) {
    __syncthreads();   // B1: drains K(t) GL16s; all waves past buf^1 reads

    // ---- stage K(t+1) into the idle buffer (drains under this tile) ----
    if (it + 1 < iters) {
      size_t tb = (size_t)(n0 + 32) << 9;
      const char* gk = (const char*)gkhi + tb + wo;
      const char* gl = (const char*)gklo + tb + wo;
      char* lk = (char*)sm.khi[cur ^ 1] + (wave << 12);
      char* ll = (char*)sm.klo[cur ^ 1] + (wave << 12);
      GL16(gk,        lk);        GL16(gk + 1024, lk + 1024);
      GL16(gk + 2048, lk + 2048); GL16(gk + 3072, lk + 3072);
      GL16(gl,        ll);        GL16(gl + 1024, ll + 1024);
      GL16(gl + 2048, ll + 2048); GL16(gl + 3072, ll + 3072);
    }
    float s2a = gs2[n0 + lr], s2b = gs2[n0 + 16 + lr];

    // ---- QK^T (3-pass split bf16); -0.5||s||^2 folded into softmax ----
    const u16* kbh = sm.khi[cur];
    const u16* kbl = sm.klo[cur];
    f32x4 acc[2];
    acc[0] = (f32x4){0.f, 0.f, 0.f, 0.f};
    acc[1] = (f32x4){0.f, 0.f, 0.f, 0.f};
    __builtin_amdgcn_s_setprio(1);
#pragma unroll
    for (int nt = 0; nt < 2; ++nt) {
#pragma unroll
      for (int ks = 0; ks < 8; ++ks) {
        int co = (((ks << 2) + lq) ^ krsw) << 3;
        const s16x8 bh = *(const s16x8*)&kbh[(nt * 16 + lr) * 256 + co];
        const s16x8 bl = *(const s16x8*)&kbl[(nt * 16 + lr) * 256 + co];
        acc[nt] = __builtin_amdgcn_mfma_f32_16x16x32_bf16(qhi[ks], bh, acc[nt], 0, 0, 0);
        acc[nt] = __builtin_amdgcn_mfma_f32_16x16x32_bf16(qlo[ks], bh, acc[nt], 0, 0, 0);
        acc[nt] = __builtin_amdgcn_mfma_f32_16x16x32_bf16(qhi[ks], bl, acc[nt], 0, 0, 0);
      }
    }
    __builtin_amdgcn_s_setprio(0);

    // ---- online softmax (defer-max) + P->LDS (wave-private) ----
#pragma unroll
    for (int r = 0; r < 4; ++r) {
      float L[2];
      L[0] = (acc[0][r] - s2a) * invd[r];
      L[1] = (acc[1][r] - s2b) * invd[r];
      float tmax = fmaxf(L[0], L[1]);
#pragma unroll
      for (int msk = 1; msk <= 8; msk <<= 1)
        tmax = fmaxf(tmax, __shfl_xor(tmax, msk));
      float mnew = mrun[r];
      if (!__all(tmax - mnew <= DEFER_THR)) {
        mnew = fmaxf(mnew, tmax);
        float alpha = EXP2(mrun[r] - mnew);
        mrun[r] = mnew;
        lrun[r] *= alpha;
#pragma unroll
        for (int dt = 0; dt < 16; ++dt) O[dt][r] *= alpha;
      }
      float ps = 0.f;
#pragma unroll
      for (int nt = 0; nt < 2; ++nt) {
        u16 pq = bf16_rne(EXP2(L[nt] - mnew));
        ps += bf16_to_f(pq);   // sum the QUANTIZED p: consistent with PV
        sm.p[wave][(lq * 4 + r) * PSTR + nt * 16 + lr] = pq;
      }
#pragma unroll
      for (int msk = 1; msk <= 8; msk <<= 1) ps += __shfl_xor(ps, msk);
      lrun[r] += ps;
    }

    // ---- PV: O += P @ V, V read DIRECTLY from global (L2-resident slice;
    //      1KB fully-coalesced per b128: lanes span 16 rows x 64B) ----
    {
      const s16x8 pa = *(const s16x8*)&sm.p[wave][lr * PSTR + lq * 8];
      const u16* gvb = gvt + (size_t)(n0 >> 5) * 8192;   // tile base, u16 units
      __builtin_amdgcn_s_setprio(1);
#pragma unroll
      for (int dt = 0; dt < 16; ++dt) {
        int row = dt * 16 + lr;
        const s16x8 bv = *(const s16x8*)&gvb[row * 32 + lq * 8];
        O[dt] = __builtin_amdgcn_mfma_f32_16x16x32_bf16(pa, bv, O[dt], 0, 0, 0);
      }
      __builtin_amdgcn_s_setprio(0);
    }
    cur ^= 1;
    n0 += 32;
  }

  // ---- epilogue ----
  if (nsplit == 1) {
#pragma unroll
    for (int r = 0; r < 4; ++r) {
      int gm = m0 + lq * 4 + r;
      float tv = load_t(t, gm, tmode);
      float ts = EXP2(fmaf(tv, L2_10K, L2_001));
      float den = ts * ts + SMIN2;
      float sc = ts / den;
      float il = 1.f / lrun[r];
#pragma unroll
      for (int dt = 0; dt < 16; ++dt) {
        int d = dt * 16 + lr;
        out[(size_t)gm * DDIM + d] = sc * (O[dt][r] * il - x[(size_t)gm * DDIM + d]);
      }
    }
  } else {
    size_t obase = (size_t)split * B * DDIM;
#pragma unroll
    for (int r = 0; r < 4; ++r) {
      int gm = m0 + lq * 4 + r;
#pragma unroll
      for (int dt = 0; dt < 16; ++dt)
        pO[obase + (size_t)gm * DDIM + dt * 16 + lr] = O[dt][r];
      if (lr == 0) {
        pm[(size_t)split * B + gm] = mrun[r];
        pl[(size_t)split * B + gm] = lrun[r];
      }
    }
  }
}

// ---------------- combine (float4) ----------------
__global__ __launch_bounds__(256)
void combine_kernel(const void* __restrict__ t, const float* __restrict__ x,
                    const float* __restrict__ pO, const float* __restrict__ pm,
                    const float* __restrict__ pl, float* __restrict__ out,
                    const int* __restrict__ tflag, int nsplit, int B)
{
  int idx = blockIdx.x * 256 + threadIdx.x;   // over B*64 float4s
  int b = idx >> 6;
  const int tmode = *tflag;
  float M = -1e30f;
  for (int s = 0; s < nsplit; ++s) M = fmaxf(M, pm[(size_t)s * B + b]);
  float4 num = {0.f, 0.f, 0.f, 0.f};
  float den = 0.f;
  for (int s = 0; s < nsplit; ++s) {
    float w = EXP2(pm[(size_t)s * B + b] - M);
    float4 po = ((const float4*)pO)[(size_t)s * B * 64 + idx];
    num.x += w * po.x; num.y += w * po.y; num.z += w * po.z; num.w += w * po.w;
    den += w * pl[(size_t)s * B + b];
  }
  float il = 1.f / den;
  float tv = load_t(t, b, tmode);
  float ts = EXP2(fmaf(tv, L2_10K, L2_001));
  float sc = ts / (ts * ts + SMIN2);
  float4 xx = ((const float4*)x)[idx];
  float4 o;
  o.x = sc * (num.x * il - xx.x);
  o.y = sc * (num.y * il - xx.y);
  o.z = sc * (num.z * il - xx.z);
  o.w = sc * (num.w * il - xx.w);
  ((float4*)out)[idx] = o;
}

extern "C" void kernel_launch(void* const* d_in, const int* in_sizes, int n_in,
                              void* d_out, int out_size, void* d_ws, size_t ws_size,
                              hipStream_t stream) {
  // Identify inputs BY SIZE: x has out_size elements, samples largest, t smallest.
  int xi = 0, si = 0, ti = 0;
  for (int i = 0; i < 3; ++i) {
    if (in_sizes[i] == out_size) xi = i;
    if (in_sizes[i] > in_sizes[si]) si = i;
    if (in_sizes[i] < in_sizes[ti]) ti = i;
  }
  const void*  t   = d_in[ti];                  // fp32 [B]
  const float* x   = (const float*)d_in[xi];    // fp32 [B,256]
  const float* smp = (const float*)d_in[si];    // fp32 [N,256]
  float* out = (float*)d_out;                   // fp32 [B,256]
  int B = out_size / DDIM;          // 4096
  int N = in_sizes[si] / DDIM;      // 8192

  // ws layout: gkhi | gklo | gvt | gs2 | tflag(+pad to 16B) | pO | pm | pl
  size_t plane = (size_t)N * DDIM;              // elements per u16 plane
  u16*   gkhi = (u16*)d_ws;
  u16*   gklo = gkhi + plane;
  u16*   gvt  = gklo + plane;
  float* gs2  = (float*)(gvt + plane);
  int*   tflag = (int*)(gs2 + N);
  float* pO   = gs2 + N + 4;                    // keep 16B alignment for float4
  size_t fixed = plane * 6 + (size_t)N * 4 + 16;  // bytes
  size_t per = (size_t)B * DDIM * sizeof(float) + (size_t)B * 2 * sizeof(float);

  // ns=8: 512 blocks = exactly 2 blocks/CU, no scheduling tail.
  const int cand[4] = {8, 4, 2, 1};
  int ns = 1;
  for (int i = 0; i < 4; ++i)
    if (fixed + (size_t)cand[i] * per <= ws_size) { ns = cand[i]; break; }
  float* pm = pO + (size_t)ns * B * DDIM;
  float* pl = pm + (size_t)ns * B;

  prep_all<<<dim3(N / 4 + N / 32), 256, 0, stream>>>(smp, t, gkhi, gklo, gs2,
                                                     gvt, tflag, N);
  flash_kernel<<<dim3(B / 64, ns), 256, 0, stream>>>(t, x, gkhi, gklo, gvt, gs2, tflag,
                                                     out, pO, pm, pl, B, N);
  if (ns > 1)
    combine_kernel<<<dim3(B * 64 / 256), 256, 0, stream>>>(t, x, pO, pm, pl, out, tflag, ns, B);
}

// Round 10
// 167.357 us; speedup vs baseline: 1.3095x; 1.3095x over previous
//
#include <hip/hip_runtime.h>
#include <math.h>

// SampleScoreModel fused flash kernel — fp32 in/out.
// R19: attack the softmax/P critical path. Evidence: SQ_LDS_BANK_CONFLICT
// constant 8650752 across R11-R18 (even with vt LDS reads removed in R18) ->
// conflicts + serial cost live in the P round-trip (8x ds_write_b16 4-way
// conflicted + b128 read) and the 32 dependent shfl_xor per thread-tile.
// Fix: SWAP QK^T operands: mfma(K,Q) instead of mfma(Q,K). A/B fragment
// layouts are identical (row=lane&15, k=(lane>>4)*8+j) -> same LDS reads,
// same Q regs, zero staging changes. Output S[n][m] has m lane-local (m=lr):
//  - softmax reduce: 7 in-lane ops + 2 shfl_xor(16,32) vs 32 shuffles
//  - invd/mrun/lrun become scalars; s2 via two float4 loads (n=lq*4+r rows)
//  - P -> PV A-frag by 8 bpermutes + 4 selects (src=((lq&1)<<5)+lr, nt by
//    lq>=2); p LDS buffer DELETED (LDS 70656->65536)
//  - O layout unchanged (m=lq*4+r); alpha/il broadcast via 4 shuffles
//    (rescale-rare / epilogue-only)
// Memory skeleton = R17 verbatim (verified 127.5us flash): K single buffer +
// vt double buffer, all GL16, 2x __syncthreads per tile. R18's V-from-L2
// regressed (152.8us: ~2300cyc/tile synchronous L2 reads in PV) -> reverted.
// prep merged (R18) with R17's vt store swizzle restored.

typedef float  f32x4 __attribute__((ext_vector_type(4)));
typedef short  s16x8 __attribute__((ext_vector_type(8)));
typedef unsigned int u32x4 __attribute__((ext_vector_type(4)));
typedef unsigned short u16;

#define LOG2E   1.44269504088896f
#define L2_10K  13.2877123795494f   /* log2(10000) */
#define L2_001 -6.64385618977472f   /* log2(0.01)  */
#define SMIN2   1e-8f               /* SIGMA_MIN^2 */
#define DDIM    256
#define DEFER_THR 12.0f             /* log2-domain defer-max threshold */

#if defined(__has_builtin)
#if __has_builtin(__builtin_amdgcn_exp2f)
#define EXP2(x) __builtin_amdgcn_exp2f(x)
#endif
#endif
#ifndef EXP2
#define EXP2(x) exp2f(x)
#endif

// global -> LDS direct copy, 16B/lane. offset=0 ALWAYS (R15 lesson).
#define GL16(gp, lp) \
  __builtin_amdgcn_global_load_lds( \
      (const __attribute__((address_space(1))) unsigned int*)(gp), \
      (__attribute__((address_space(3))) unsigned int*)(lp), 16, 0, 0)

__device__ __forceinline__ u16 bf16_rne(float f) {
  unsigned int u = __builtin_bit_cast(unsigned int, f);
  u = (u + 0x7FFFu + ((u >> 16) & 1u)) >> 16;
  return (u16)u;
}
__device__ __forceinline__ float bf16_to_f(u16 h) {
  unsigned int u = ((unsigned int)h) << 16;
  return __builtin_bit_cast(float, u);
}
__device__ __forceinline__ float f16_to_f(u16 h) {
  int s = (h >> 15) & 1, e = (h >> 10) & 31, m = h & 1023;
  float v;
  if (e == 0)       v = ldexpf((float)m, -24);
  else if (e == 31) v = 3.0e38f;
  else              v = ldexpf((float)(1024 + m), e - 25);
  return s ? -v : v;
}

// t-dtype insurance (returns fp32-mode on genuine fp32 t~U[0,1)).
__device__ __forceinline__ int classify_t_dtype(const void* tp) {
  const u16*          u16p = (const u16*)tp;
  const unsigned int* u32p = (const unsigned int*)tp;
  int c16 = 0, c32 = 0;
  for (int i = 0; i < 128; ++i) {
    u16 u = u16p[i];
    int e = (u >> 7) & 0xFF;
    if (!(u & 0x8000) && e >= 113 && e <= 126) c16++;
  }
  for (int i = 0; i < 64; ++i) {
    unsigned int w = u32p[i];
    int e = (int)((w >> 23) & 0xFF);
    if (!(w & 0x80000000u) && e >= 113 && e <= 126) c32++;
  }
  if (c32 >= 51) return (c16 >= 102) ? 0 : 1;   // 0=bf16, 1=fp32
  return 2;                                      // 2=fp16
}
__device__ __forceinline__ float load_t(const void* tp, int i, int mode) {
  float v;
  if (mode == 0)      v = bf16_to_f(((const u16*)tp)[i]);
  else if (mode == 1) v = ((const float*)tp)[i];
  else                v = f16_to_f(((const u16*)tp)[i]);
  return fminf(fmaxf(v, 0.f), 1.f);
}

// ---------------- merged precompute kernel ----------------
// Blocks [0, N/4):        bf16 hi/lo K planes, PRE-SWIZZLED (chunk ci at
//                         slot ci^(row&7)), + 0.5*||s||^2, + t-dtype flag.
// Blocks [N/4, N/4+N/32): transposed V (bf16 hi), PRE-SWIZZLED for the LDS
//                         read: d-row's chunk c at slot c^((d>>1)&3).
__global__ __launch_bounds__(256)
void prep_all(const float* __restrict__ smp, const void* __restrict__ t,
              u16* __restrict__ gkhi, u16* __restrict__ gklo,
              float* __restrict__ gs2, u16* __restrict__ gvt,
              int* __restrict__ tflag, int N)
{
  int nb_rows = N >> 2;
  if ((int)blockIdx.x < nb_rows) {
    if (blockIdx.x == 0 && threadIdx.x == 0) *tflag = classify_t_dtype(t);
    int row  = blockIdx.x * 4 + (threadIdx.x >> 6);
    int lane = threadIdx.x & 63;
    float4 v4 = *(const float4*)(smp + (size_t)row * DDIM + lane * 4);
    float v[4] = {v4.x, v4.y, v4.z, v4.w};
    ushort4 h, l;
    u16 hh[4], ll[4];
    float s2 = 0.f;
#pragma unroll
    for (int e = 0; e < 4; ++e) {
      hh[e] = bf16_rne(v[e]);
      ll[e] = bf16_rne(v[e] - bf16_to_f(hh[e]));
      s2 = fmaf(v[e], v[e], s2);
    }
    h.x = hh[0]; h.y = hh[1]; h.z = hh[2]; h.w = hh[3];
    l.x = ll[0]; l.y = ll[1]; l.z = ll[2]; l.w = ll[3];
    int ci  = lane >> 1;                                  // chunk 0..31
    int col = (((ci ^ (row & 7)) << 3) | ((lane & 1) << 2));
    *(ushort4*)(gkhi + (size_t)row * DDIM + col) = h;
    *(ushort4*)(gklo + (size_t)row * DDIM + col) = l;
#pragma unroll
    for (int msk = 1; msk <= 32; msk <<= 1) s2 += __shfl_xor(s2, msk);
    if (lane == 0) gs2[row] = 0.5f * s2;
  } else {
    int bt = blockIdx.x - nb_rows;
    int d  = threadIdx.x;
    int n0 = bt * 32;
    u16 buf[32];
#pragma unroll
    for (int i = 0; i < 32; ++i)
      buf[i] = bf16_rne(smp[(size_t)(n0 + i) * DDIM + d]);  // coalesced
    u16* dst = gvt + ((size_t)bt * 256 + d) * 32;
    int vkey = (d >> 1) & 3;
#pragma unroll
    for (int c = 0; c < 4; ++c)
      *(s16x8*)(dst + ((c ^ vkey) << 3)) = *(s16x8*)&buf[c * 8];
  }
}

// ---------------- flash kernel ----------------

struct __align__(16) Smem {
  u16 khi[32 * 256];     // 16384 B  swizzled image: slot s of row r = chunk s^(r&7)
  u16 klo[32 * 256];     // 16384 B
  u16 vt [2][256 * 32];  // 32768 B  dbuf; slot s of d-row = chunk s^((d>>1)&3)
};  // 65536 B -> 2 blocks/CU

__global__ __launch_bounds__(256, 2)
void flash_kernel(const void* __restrict__ t, const float* __restrict__ x,
                  const u16* __restrict__ gkhi, const u16* __restrict__ gklo,
                  const u16* __restrict__ gvt, const float* __restrict__ gs2,
                  const int* __restrict__ tflag, float* __restrict__ out,
                  float* __restrict__ pO, float* __restrict__ pm,
                  float* __restrict__ pl, int B, int N)
{
  __shared__ Smem sm;
  const int tid  = threadIdx.x;
  const int wave = tid >> 6, lane = tid & 63;
  const int lq = lane >> 4, lr = lane & 15;      // quad, lane-in-quad
  const int m0 = blockIdx.x * 64 + wave * 16;    // wave owns 16 m-rows
  const int nsplit = gridDim.y, split = blockIdx.y;
  const int tiles_total = N >> 5;
  const int tq = tiles_total / nsplit, tr = tiles_total % nsplit;
  const int tile0 = split * tq + (split < tr ? split : tr);
  const int iters = tq + (split < tr ? 1 : 0);
  const int n0b = tile0 << 5;
  const int tmode = *tflag;

  // per-lane m = m0 + lr (swapped-QK layout) -> scalar t-state
  float invd;
  {
    float tv = load_t(t, m0 + lr, tmode);
    float ts = EXP2(fmaf(tv, L2_10K, L2_001));
    invd = LOG2E / (ts * ts + SMIN2);
  }

  // Q fragments: B-operand layout = lane holds Q[m=lr][k=lq*8+j] — identical
  // data placement to the old A-frag load (layout symmetry), unchanged.
  s16x8 qhi[8], qlo[8];
  {
    const float* xr = x + (size_t)(m0 + lr) * DDIM;
#pragma unroll
    for (int ks = 0; ks < 8; ++ks) {
      const float4* p4 = (const float4*)(xr + ks * 32 + lq * 8);
      float4 a = p4[0], b = p4[1];
      float v[8] = {a.x, a.y, a.z, a.w, b.x, b.y, b.z, b.w};
#pragma unroll
      for (int j = 0; j < 8; ++j) {
        u16 h = bf16_rne(v[j]);
        u16 l = bf16_rne(v[j] - bf16_to_f(h));
        qhi[ks][j] = (short)h;
        qlo[ks][j] = (short)l;
      }
    }
  }

  f32x4 O[16];
#pragma unroll
  for (int dt = 0; dt < 16; ++dt) O[dt] = (f32x4){0.f, 0.f, 0.f, 0.f};
  float mrun = -1e30f, lrun = 0.f;               // per-lane m = m0+lr

  const int krsw = lr & 7;                       // K read swizzle key (row&7)
  const int wo = (wave << 12) + lane * 16;       // GL16 wave slice + lane off
  const int lq4 = lq << 2;

  {  // prologue: stage K(t0) + vt[0](t0) via GL16 (R17 verbatim)
    size_t tb = (size_t)n0b << 9;
    const char* gk = (const char*)gkhi + tb + wo;
    const char* gl = (const char*)gklo + tb + wo;
    const char* gv = (const char*)gvt  + tb + wo;
    char* lk = (char*)sm.khi   + (wave << 12);
    char* ll = (char*)sm.klo   + (wave << 12);
    char* lv = (char*)sm.vt[0] + (wave << 12);
    GL16(gk,        lk);        GL16(gk + 1024, lk + 1024);
    GL16(gk + 2048, lk + 2048); GL16(gk + 3072, lk + 3072);
    GL16(gl,        ll);        GL16(gl + 1024, ll + 1024);
    GL16(gl + 2048, ll + 2048); GL16(gl + 3072, ll + 3072);
    GL16(gv,        lv);        GL16(gv + 1024, lv + 1024);
    GL16(gv + 2048, lv + 2048); GL16(gv + 3072, lv + 3072);
  }

  int n0 = n0b, cur = 0;
  for (int it = 0; it < iters; ++it) {
    __syncthreads();   // B1: drains K(t)+vt[cur](t) GL16s

    // s2 rows matching this lane's acc n-indices (n = nt*16 + lq*4 + r)
    float4 s2a4 = *(const float4*)(gs2 + n0 + lq4);
    float4 s2b4 = *(const float4*)(gs2 + n0 + 16 + lq4);

    // ---- QK^T SWAPPED (A=K, B=Q): D[n][m], m = lr lane-local ----
    f32x4 acc[2];
    acc[0] = (f32x4){0.f, 0.f, 0.f, 0.f};
    acc[1] = (f32x4){0.f, 0.f, 0.f, 0.f};
    __builtin_amdgcn_s_setprio(1);
#pragma unroll
    for (int nt = 0; nt < 2; ++nt) {
#pragma unroll
      for (int ks = 0; ks < 8; ++ks) {
        int co = (((ks << 2) + lq) ^ krsw) << 3;
        const s16x8 bh = *(const s16x8*)&sm.khi[(nt * 16 + lr) * 256 + co];
        const s16x8 bl = *(const s16x8*)&sm.klo[(nt * 16 + lr) * 256 + co];
        acc[nt] = __builtin_amdgcn_mfma_f32_16x16x32_bf16(bh, qhi[ks], acc[nt], 0, 0, 0);
        acc[nt] = __builtin_amdgcn_mfma_f32_16x16x32_bf16(bh, qlo[ks], acc[nt], 0, 0, 0);
        acc[nt] = __builtin_amdgcn_mfma_f32_16x16x32_bf16(bl, qhi[ks], acc[nt], 0, 0, 0);
      }
    }
    __builtin_amdgcn_s_setprio(0);

    __syncthreads();   // B2: all waves done reading K buffer

    // ---- stage next tile: K -> single buffer, vt -> idle buffer ----
    if (it + 1 < iters) {
      size_t tb = (size_t)(n0 + 32) << 9;
      const char* gk = (const char*)gkhi + tb + wo;
      const char* gl = (const char*)gklo + tb + wo;
      const char* gv = (const char*)gvt  + tb + wo;
      char* lk = (char*)sm.khi + (wave << 12);
      char* ll = (char*)sm.klo + (wave << 12);
      char* lv = (char*)sm.vt[cur ^ 1] + (wave << 12);
      GL16(gk,        lk);        GL16(gk + 1024, lk + 1024);
      GL16(gk + 2048, lk + 2048); GL16(gk + 3072, lk + 3072);
      GL16(gl,        ll);        GL16(gl + 1024, ll + 1024);
      GL16(gl + 2048, ll + 2048); GL16(gl + 3072, ll + 3072);
      GL16(gv,        lv);        GL16(gv + 1024, lv + 1024);
      GL16(gv + 2048, lv + 2048); GL16(gv + 3072, lv + 3072);
    }

    // ---- in-lane online softmax (m = lr fixed per lane) ----
    float L0[4], L1[4];
    float tmax = -1e30f;
#pragma unroll
    for (int r = 0; r < 4; ++r) {
      L0[r] = (acc[0][r] - s2a4[r]) * invd;      // n = lq*4+r
      L1[r] = (acc[1][r] - s2b4[r]) * invd;      // n = 16+lq*4+r
      tmax = fmaxf(tmax, fmaxf(L0[r], L1[r]));
    }
    tmax = fmaxf(tmax, __shfl_xor(tmax, 16));
    tmax = fmaxf(tmax, __shfl_xor(tmax, 32));
    float mnew = mrun;
    if (!__all(tmax - mnew <= DEFER_THR)) {
      mnew = fmaxf(mrun, tmax);
      float alpha = EXP2(mrun - mnew);
      mrun = mnew;
      lrun *= alpha;
      // O's m = lq*4+r -> fetch alpha from lane holding that m (lanes 0..15)
      float a0 = __shfl(alpha, lq4 + 0), a1 = __shfl(alpha, lq4 + 1);
      float a2 = __shfl(alpha, lq4 + 2), a3 = __shfl(alpha, lq4 + 3);
#pragma unroll
      for (int dt = 0; dt < 16; ++dt) {
        O[dt][0] *= a0; O[dt][1] *= a1; O[dt][2] *= a2; O[dt][3] *= a3;
      }
    }
    u16 p0[4], p1[4];
    float ps = 0.f;
#pragma unroll
    for (int r = 0; r < 4; ++r) {
      p0[r] = bf16_rne(EXP2(L0[r] - mnew));
      p1[r] = bf16_rne(EXP2(L1[r] - mnew));
      ps += bf16_to_f(p0[r]) + bf16_to_f(p1[r]); // sum QUANTIZED p
    }
    ps += __shfl_xor(ps, 16);
    ps += __shfl_xor(ps, 32);
    lrun += ps;

    // ---- P -> PV A-frag: lane needs P[m=lr][n=lq*8+j], j=0..7.
    //      Holds P[n=nt*16+lq*4+r][m=lr]. 8 bpermutes + 4 selects. ----
    s16x8 pa;
    {
      unsigned A0 = (unsigned)p0[0] | ((unsigned)p0[1] << 16);
      unsigned A1 = (unsigned)p0[2] | ((unsigned)p0[3] << 16);
      unsigned B0 = (unsigned)p1[0] | ((unsigned)p1[1] << 16);
      unsigned B1 = (unsigned)p1[2] | ((unsigned)p1[3] << 16);
      int s0 = ((lq & 1) << 5) + lr;   // src lane group 2*(lq&1)
      int s1 = s0 + 16;
      unsigned xa0 = (unsigned)__shfl((int)A0, s0);
      unsigned xa1 = (unsigned)__shfl((int)A1, s0);
      unsigned xa2 = (unsigned)__shfl((int)A0, s1);
      unsigned xa3 = (unsigned)__shfl((int)A1, s1);
      unsigned xb0 = (unsigned)__shfl((int)B0, s0);
      unsigned xb1 = (unsigned)__shfl((int)B1, s0);
      unsigned xb2 = (unsigned)__shfl((int)B0, s1);
      unsigned xb3 = (unsigned)__shfl((int)B1, s1);
      u32x4 pw;
      pw.x = (lq < 2) ? xa0 : xb0;
      pw.y = (lq < 2) ? xa1 : xb1;
      pw.z = (lq < 2) ? xa2 : xb2;
      pw.w = (lq < 2) ? xa3 : xb3;
      pa = __builtin_bit_cast(s16x8, pw);
    }

    // ---- PV: O += P @ V  (vt[cur], staged last tile, drained at B1) ----
    {
      const u16* vtc = sm.vt[cur];
      __builtin_amdgcn_s_setprio(1);
#pragma unroll
      for (int dt = 0; dt < 16; ++dt) {
        int row = dt * 16 + lr;
        const s16x8 bv = *(const s16x8*)&vtc[(row << 5) + ((lq ^ ((row >> 1) & 3)) << 3)];
        O[dt] = __builtin_amdgcn_mfma_f32_16x16x32_bf16(pa, bv, O[dt], 0, 0, 0);
      }
      __builtin_amdgcn_s_setprio(0);
    }
    cur ^= 1;
    n0 += 32;
  }

  // ---- epilogue ----
  if (nsplit == 1) {
    float inv = 1.f / lrun;
    float il0 = __shfl(inv, lq4 + 0), il1 = __shfl(inv, lq4 + 1);
    float il2 = __shfl(inv, lq4 + 2), il3 = __shfl(inv, lq4 + 3);
    float il[4] = {il0, il1, il2, il3};
#pragma unroll
    for (int r = 0; r < 4; ++r) {
      int gm = m0 + lq4 + r;
      float tv = load_t(t, gm, tmode);
      float ts = EXP2(fmaf(tv, L2_10K, L2_001));
      float den = ts * ts + SMIN2;
      float sc = ts / den;
#pragma unroll
      for (int dt = 0; dt < 16; ++dt) {
        int d = dt * 16 + lr;
        out[(size_t)gm * DDIM + d] = sc * (O[dt][r] * il[r] - x[(size_t)gm * DDIM + d]);
      }
    }
  } else {
    size_t obase = (size_t)split * B * DDIM;
#pragma unroll
    for (int r = 0; r < 4; ++r) {
      int gm = m0 + lq4 + r;
#pragma unroll
      for (int dt = 0; dt < 16; ++dt)
        pO[obase + (size_t)gm * DDIM + dt * 16 + lr] = O[dt][r];
    }
    if (lane < 16) {
      pm[(size_t)split * B + m0 + lane] = mrun;
      pl[(size_t)split * B + m0 + lane] = lrun;
    }
  }
}

// ---------------- combine (float4) ----------------
__global__ __launch_bounds__(256)
void combine_kernel(const void* __restrict__ t, const float* __restrict__ x,
                    const float* __restrict__ pO, const float* __restrict__ pm,
                    const float* __restrict__ pl, float* __restrict__ out,
                    const int* __restrict__ tflag, int nsplit, int B)
{
  int idx = blockIdx.x * 256 + threadIdx.x;   // over B*64 float4s
  int b = idx >> 6;
  const int tmode = *tflag;
  float M = -1e30f;
  for (int s = 0; s < nsplit; ++s) M = fmaxf(M, pm[(size_t)s * B + b]);
  float4 num = {0.f, 0.f, 0.f, 0.f};
  float den = 0.f;
  for (int s = 0; s < nsplit; ++s) {
    float w = EXP2(pm[(size_t)s * B + b] - M);
    float4 po = ((const float4*)pO)[(size_t)s * B * 64 + idx];
    num.x += w * po.x; num.y += w * po.y; num.z += w * po.z; num.w += w * po.w;
    den += w * pl[(size_t)s * B + b];
  }
  float il = 1.f / den;
  float tv = load_t(t, b, tmode);
  float ts = EXP2(fmaf(tv, L2_10K, L2_001));
  float sc = ts / (ts * ts + SMIN2);
  float4 xx = ((const float4*)x)[idx];
  float4 o;
  o.x = sc * (num.x * il - xx.x);
  o.y = sc * (num.y * il - xx.y);
  o.z = sc * (num.z * il - xx.z);
  o.w = sc * (num.w * il - xx.w);
  ((float4*)out)[idx] = o;
}

extern "C" void kernel_launch(void* const* d_in, const int* in_sizes, int n_in,
                              void* d_out, int out_size, void* d_ws, size_t ws_size,
                              hipStream_t stream) {
  // Identify inputs BY SIZE: x has out_size elements, samples largest, t smallest.
  int xi = 0, si = 0, ti = 0;
  for (int i = 0; i < 3; ++i) {
    if (in_sizes[i] == out_size) xi = i;
    if (in_sizes[i] > in_sizes[si]) si = i;
    if (in_sizes[i] < in_sizes[ti]) ti = i;
  }
  const void*  t   = d_in[ti];                  // fp32 [B]
  const float* x   = (const float*)d_in[xi];    // fp32 [B,256]
  const float* smp = (const float*)d_in[si];    // fp32 [N,256]
  float* out = (float*)d_out;                   // fp32 [B,256]
  int B = out_size / DDIM;          // 4096
  int N = in_sizes[si] / DDIM;      // 8192

  // ws layout: gkhi | gklo | gvt | gs2 | tflag(+pad to 16B) | pO | pm | pl
  size_t plane = (size_t)N * DDIM;              // elements per u16 plane
  u16*   gkhi = (u16*)d_ws;
  u16*   gklo = gkhi + plane;
  u16*   gvt  = gklo + plane;
  float* gs2  = (float*)(gvt + plane);
  int*   tflag = (int*)(gs2 + N);
  float* pO   = gs2 + N + 4;                    // keep 16B alignment for float4
  size_t fixed = plane * 6 + (size_t)N * 4 + 16;  // bytes
  size_t per = (size_t)B * DDIM * sizeof(float) + (size_t)B * 2 * sizeof(float);

  // ns=8: 512 blocks = exactly 2 blocks/CU, no scheduling tail.
  const int cand[4] = {8, 4, 2, 1};
  int ns = 1;
  for (int i = 0; i < 4; ++i)
    if (fixed + (size_t)cand[i] * per <= ws_size) { ns = cand[i]; break; }
  float* pm = pO + (size_t)ns * B * DDIM;
  float* pl = pm + (size_t)ns * B;

  prep_all<<<dim3(N / 4 + N / 32), 256, 0, stream>>>(smp, t, gkhi, gklo, gs2,
                                                     gvt, tflag, N);
  flash_kernel<<<dim3(B / 64, ns), 256, 0, stream>>>(t, x, gkhi, gklo, gvt, gs2, tflag,
                                                     out, pO, pm, pl, B, N);
  if (ns > 1)
    combine_kernel<<<dim3(B * 64 / 256), 256, 0, stream>>>(t, x, pO, pm, pl, out, tflag, ns, B);
}